// Round 12
// baseline (1146.724 us; speedup 1.0000x reference)
//
#include <hip/hip_runtime.h>
#include <hip/hip_fp16.h>
#include <math.h>

#define C_CLS 40
#define RPB 6   // rows per 256-thread block in scale_kernel

struct __align__(8) H4 { __half2 a; __half2 b; };  // 4 halves

// packed edge: low 17 bits = col (N < 2^17), high 15 bits = fp16 weight
// without sign bit (weights always >= 0).
static __device__ __forceinline__ float h15f(unsigned b) {
  union { unsigned short s; __half h; } u;
  u.s = (unsigned short)b;
  return __half2float(u.h);
}
static __device__ __forceinline__ unsigned f2h15(float w) {
  union { __half h; unsigned short s; } u;
  u.h = __float2half_rn(w);
  return (unsigned)u.s;  // sign bit is 0 for w >= 0
}

// ---- runtime mask element-size handling ------------------------------------
static __device__ __forceinline__ bool load_mask(const void* p, int esz, int i) {
  if (esz == 1) return ((const unsigned char*)p)[i] != 0;
  return ((const unsigned int*)p)[i] != 0u;  // works for int32 0/1 and f32 0.0/1.0
}

__global__ void detect_kernel(const unsigned int* m, int* flag) {
  __shared__ int bad;
  if (threadIdx.x == 0) bad = 0;
  __syncthreads();
  unsigned int v = m[threadIdx.x];
  if (!(v == 0u || v == 1u || v == 0x3F800000u)) bad = 1;  // benign race
  __syncthreads();
  if (threadIdx.x == 0) flag[0] = bad ? 1 : 4;  // element size in bytes
}

// ---- CSR build with per-row column-half split ------------------------------
// Segment idx = (row<<1) | (col >= half). Gives each row two sub-segments so
// prop steps can run as two column-localized passes (gather footprint halves,
// per-XCD L2 hit rate up).
__global__ void hist_kernel(const int* __restrict__ row, const int* __restrict__ col,
                            int* __restrict__ cnt2, int E, int half) {
  int e = blockIdx.x * blockDim.x + threadIdx.x;
  if (e < E) atomicAdd(&cnt2[(row[e] << 1) | (col[e] >= half ? 1 : 0)], 1);
}

__global__ void scan1_kernel(const int* __restrict__ cnt, int* __restrict__ rp,
                             int* __restrict__ part, int n2) {
  __shared__ int sh[256];
  int gid = blockIdx.x * 256 + threadIdx.x;
  int v = (gid < n2) ? cnt[gid] : 0;
  sh[threadIdx.x] = v;
  __syncthreads();
  for (int o = 1; o < 256; o <<= 1) {
    int t = (threadIdx.x >= o) ? sh[threadIdx.x - o] : 0;
    __syncthreads();
    sh[threadIdx.x] += t;
    __syncthreads();
  }
  if (gid < n2) rp[gid] = sh[threadIdx.x] - v;  // exclusive within block
  if (threadIdx.x == 255) part[blockIdx.x] = sh[255];
}

__global__ void scan2_kernel(int* part, int B) {
  __shared__ int sh[1024];
  int t = threadIdx.x;
  int v = (t < B) ? part[t] : 0;
  sh[t] = v;
  __syncthreads();
  for (int o = 1; o < 1024; o <<= 1) {
    int u = (t >= o) ? sh[t - o] : 0;
    __syncthreads();
    sh[t] += u;
    __syncthreads();
  }
  if (t < B) part[t] = sh[t] - v;  // exclusive block offsets
}

__global__ void scan3_kernel(int* __restrict__ rp, int* __restrict__ cur,
                             const int* __restrict__ part, int n2, int E) {
  int gid = blockIdx.x * 256 + threadIdx.x;
  if (gid < n2) {
    int v = rp[gid] + part[blockIdx.x];
    rp[gid] = v;
    cur[gid] = v;
  }
  if (gid == 0) rp[n2] = E;
}

__global__ void scatter_kernel(const int* __restrict__ row, const int* __restrict__ col,
                               const float* __restrict__ w, int* __restrict__ cursor,
                               unsigned* __restrict__ eg, int E, int half) {
  int e = blockIdx.x * blockDim.x + threadIdx.x;
  if (e < E) {
    int r = row[e], c = col[e];
    int pos = atomicAdd(&cursor[(r << 1) | (c >= half ? 1 : 0)], 1);
    eg[pos] = (unsigned)c | (f2h15(w[e]) << 17);
  }
}

// deg over both sub-segments [rp2[2i], rp2[2i+2]); dis = rsqrt(deg).
__global__ void deg_rsqrt_kernel(const unsigned* __restrict__ eg, const int* __restrict__ rp2,
                                 float* __restrict__ dis, int n) {
  int i = blockIdx.x * blockDim.x + threadIdx.x;
  if (i < n) {
    float s = 0.f;
    int e1 = rp2[2 * i + 2];
    for (int e = rp2[2 * i]; e < e1; ++e) s += h15f(eg[e] >> 17);
    dis[i] = (s > 0.f) ? rsqrtf(s) : 0.f;
  }
}

// w' = dis[r] * w * dis[c], re-encoded in place.
__global__ void norm_kernel(unsigned* __restrict__ eg, const int* __restrict__ rp2,
                            const float* __restrict__ dis, int n) {
  int i = blockIdx.x * blockDim.x + threadIdx.x;
  if (i < n) {
    float dr = dis[i];
    int e1 = rp2[2 * i + 2];
    for (int e = rp2[2 * i]; e < e1; ++e) {
      unsigned u = eg[e];
      unsigned c = u & 0x1FFFFu;
      float w = dr * h15f(u >> 17) * dis[c];
      eg[e] = c | (f2h15(w) << 17);
    }
  }
}

// ---- error init (fp16-padded rows) + sigma numerator + mask count ----------
__global__ void __launch_bounds__(256) init_error_kernel(
    H4* __restrict__ x16, const float4* __restrict__ ysoft4,
    const int* __restrict__ ytrue, const void* maskp,
    const int* __restrict__ flag, float* __restrict__ sig,
    int* __restrict__ numel, int n) {
  const int esz = flag[0];
  const int total = n * 10;  // H4 chunks
  float asum = 0.f;
  int cnt = 0;
  for (int q = blockIdx.x * blockDim.x + threadIdx.x; q < total;
       q += gridDim.x * blockDim.x) {
    int i = q / 10;
    int c4 = q - i * 10;
    float4 e = make_float4(0.f, 0.f, 0.f, 0.f);
    if (load_mask(maskp, esz, i)) {
      float4 p = ysoft4[q];
      int t = ytrue[i];
      int cb = c4 * 4;
      e.x = ((t == cb) ? 1.f : 0.f) - p.x;
      e.y = ((t == cb + 1) ? 1.f : 0.f) - p.y;
      e.z = ((t == cb + 2) ? 1.f : 0.f) - p.z;
      e.w = ((t == cb + 3) ? 1.f : 0.f) - p.w;
      if (c4 == 0) cnt++;
    }
    H4 h;
    h.a = __floats2half2_rn(e.x, e.y);
    h.b = __floats2half2_rn(e.z, e.w);
    x16[i * 16 + c4] = h;
    asum += fabsf(e.x) + fabsf(e.y) + fabsf(e.z) + fabsf(e.w);
  }
  for (int o = 32; o > 0; o >>= 1) {
    asum += __shfl_down(asum, o);
    cnt += __shfl_down(cnt, o);
  }
  __shared__ float swf[4];
  __shared__ int swi[4];
  int lane = threadIdx.x & 63, wv = threadIdx.x >> 6;
  if (lane == 0) { swf[wv] = asum; swi[wv] = cnt; }
  __syncthreads();
  if (threadIdx.x == 0) {
    atomicAdd(sig, swf[0] + swf[1] + swf[2] + swf[3]);
    atomicAdd(numel, swi[0] + swi[1] + swi[2] + swi[3]);
  }
}

// ---- gather helper: accumulate over edge range [e0, e1) --------------------
static __device__ __forceinline__ void gather_acc(const H4* __restrict__ xin, int c4,
                                                  const unsigned* __restrict__ eg,
                                                  int e0, int e1, float4& acc) {
  int e = e0;
  for (; e + 3 < e1; e += 4) {  // 4 outstanding gathers
    unsigned u0 = eg[e], u1 = eg[e + 1], u2 = eg[e + 2], u3 = eg[e + 3];
    H4 h0 = xin[(u0 & 0x1FFFFu) * 16 + c4];
    H4 h1 = xin[(u1 & 0x1FFFFu) * 16 + c4];
    H4 h2 = xin[(u2 & 0x1FFFFu) * 16 + c4];
    H4 h3 = xin[(u3 & 0x1FFFFu) * 16 + c4];
    float w0 = h15f(u0 >> 17), w1 = h15f(u1 >> 17),
          w2 = h15f(u2 >> 17), w3 = h15f(u3 >> 17);
    float2 a0 = __half22float2(h0.a), b0 = __half22float2(h0.b);
    float2 a1 = __half22float2(h1.a), b1 = __half22float2(h1.b);
    float2 a2 = __half22float2(h2.a), b2 = __half22float2(h2.b);
    float2 a3 = __half22float2(h3.a), b3 = __half22float2(h3.b);
    acc.x = fmaf(w0, a0.x, acc.x); acc.y = fmaf(w0, a0.y, acc.y);
    acc.z = fmaf(w0, b0.x, acc.z); acc.w = fmaf(w0, b0.y, acc.w);
    acc.x = fmaf(w1, a1.x, acc.x); acc.y = fmaf(w1, a1.y, acc.y);
    acc.z = fmaf(w1, b1.x, acc.z); acc.w = fmaf(w1, b1.y, acc.w);
    acc.x = fmaf(w2, a2.x, acc.x); acc.y = fmaf(w2, a2.y, acc.y);
    acc.z = fmaf(w2, b2.x, acc.z); acc.w = fmaf(w2, b2.y, acc.w);
    acc.x = fmaf(w3, a3.x, acc.x); acc.y = fmaf(w3, a3.y, acc.y);
    acc.z = fmaf(w3, b3.x, acc.z); acc.w = fmaf(w3, b3.y, acc.w);
  }
  for (; e < e1; ++e) {
    unsigned u = eg[e];
    H4 h = xin[(u & 0x1FFFFu) * 16 + c4];
    float w = h15f(u >> 17);
    float2 a = __half22float2(h.a), b = __half22float2(h.b);
    acc.x = fmaf(w, a.x, acc.x); acc.y = fmaf(w, a.y, acc.y);
    acc.z = fmaf(w, b.x, acc.z); acc.w = fmaf(w, b.y, acc.w);
  }
}

// ---- prop pass 0: partial acc over low-col sub-segment -> tmp (fp16) -------
__global__ void __launch_bounds__(320) prop_pass0(const H4* __restrict__ xin,
                                                  H4* __restrict__ tmp,
                                                  const int* __restrict__ rp2,
                                                  const unsigned* __restrict__ eg, int n) {
  const int t = threadIdx.x;
  const int lr = t / 10;       // 0..31
  const int c4 = t - lr * 10;  // 0..9
  const int i = blockIdx.x * 32 + lr;
  if (i >= n) return;
  float4 acc = make_float4(0.f, 0.f, 0.f, 0.f);
  gather_acc(xin, c4, eg, rp2[2 * i], rp2[2 * i + 1], acc);
  H4 o;
  o.a = __floats2half2_rn(acc.x, acc.y);
  o.b = __floats2half2_rn(acc.z, acc.w);
  tmp[i * 10 + c4] = o;  // 80 B/row, own-row write (coalesced)
}

// ---- prop pass 1: high-col sub-segment + partial + self + post-op ----------
// POST 0 = clip (always fp16 out); POST 1 = softmax; OUT16 selects fp16 vs
// fp32-final output layout.
template <int POST, int OUT16>
__global__ void __launch_bounds__(320) prop_pass1(const H4* __restrict__ xin,
                                                  void* __restrict__ xout,
                                                  const H4* __restrict__ tmp,
                                                  const int* __restrict__ rp2,
                                                  const unsigned* __restrict__ eg,
                                                  float alpha, int n) {
  const int t = threadIdx.x;
  const int lr = t / 10;       // 0..31
  const int c4 = t - lr * 10;  // 0..9
  const int i = blockIdx.x * 32 + lr;
  const bool active = (i < n);
  float4 v = make_float4(0.f, 0.f, 0.f, 0.f);
  if (active) {
    H4 hp = tmp[i * 10 + c4];
    float2 p0 = __half22float2(hp.a), p1 = __half22float2(hp.b);
    float4 acc = make_float4(p0.x, p0.y, p1.x, p1.y);
    gather_acc(xin, c4, eg, rp2[2 * i + 1], rp2[2 * i + 2], acc);
    H4 hs = xin[i * 16 + c4];
    float2 s0 = __half22float2(hs.a), s1 = __half22float2(hs.b);
    float beta = 1.f - alpha;
    v.x = alpha * acc.x + beta * s0.x;
    v.y = alpha * acc.y + beta * s0.y;
    v.z = alpha * acc.z + beta * s1.x;
    v.w = alpha * acc.w + beta * s1.y;
  }
  if (POST == 0) {
    if (active) {
      H4 o;
      o.a = __floats2half2_rn(fminf(1.f, fmaxf(-1.f, v.x)),
                              fminf(1.f, fmaxf(-1.f, v.y)));
      o.b = __floats2half2_rn(fminf(1.f, fmaxf(-1.f, v.z)),
                              fminf(1.f, fmaxf(-1.f, v.w)));
      ((H4*)xout)[i * 16 + c4] = o;
    }
  } else {
    __shared__ float sh[32][10];
    __shared__ float shr[32];
    float lmax = fmaxf(fmaxf(v.x, v.y), fmaxf(v.z, v.w));
    if (active) sh[lr][c4] = lmax;
    __syncthreads();
    if (active && c4 == 0) {
      float m = sh[lr][0];
#pragma unroll
      for (int k = 1; k < 10; ++k) m = fmaxf(m, sh[lr][k]);
      shr[lr] = m;
    }
    __syncthreads();
    float m = active ? shr[lr] : 0.f;
    float ex = __expf(v.x - m), ey = __expf(v.y - m),
          ez = __expf(v.z - m), ew = __expf(v.w - m);
    if (active) sh[lr][c4] = ex + ey + ez + ew;
    __syncthreads();
    if (active && c4 == 0) {
      float s = sh[lr][0];
#pragma unroll
      for (int k = 1; k < 10; ++k) s += sh[lr][k];
      shr[lr] = s;
    }
    __syncthreads();
    if (active) {
      float inv = 1.f / shr[lr];
      if (OUT16) {
        H4 o;
        o.a = __floats2half2_rn(ex * inv, ey * inv);
        o.b = __floats2half2_rn(ez * inv, ew * inv);
        ((H4*)xout)[i * 16 + c4] = o;
      } else {
        ((float4*)xout)[i * 10 + c4] =
            make_float4(ex * inv, ey * inv, ez * inv, ew * inv);
      }
    }
  }
}

// ---- scale + y_s (fp16 smoothed in, fp16-padded y_s out) -------------------
__global__ void __launch_bounds__(256) scale_kernel(const __half* __restrict__ smh,
                                                    __half* __restrict__ outh,
                                                    const float* __restrict__ ysoft,
                                                    const int* __restrict__ ytrue,
                                                    const void* maskp,
                                                    const int* __restrict__ flag,
                                                    const float* __restrict__ sig,
                                                    const int* __restrict__ numel, int n) {
  int t = threadIdx.x;
  int lr = t / C_CLS, c = t - lr * C_CLS;
  int i = blockIdx.x * RPB + lr;
  bool active = (lr < RPB) && (i < n);
  __shared__ float sh[RPB][C_CLS];
  __shared__ float shd[RPB];
  float v = 0.f;
  if (active) {
    v = __half2float(smh[i * 64 + c]);
    sh[lr][c] = fabsf(v);
  }
  __syncthreads();
  if (active && c == 0) {
    float d = 0.f;
#pragma unroll
    for (int k = 0; k < C_CLS; ++k) d += sh[lr][k];
    shd[lr] = d;
  }
  __syncthreads();
  if (active) {
    float denom = shd[lr];
    float sigma = sig[0] / (float)numel[0];
    float raw = sigma / ((denom > 0.f) ? denom : 1.f);
    float scale = (denom <= 0.f || raw > 1000.f) ? 1.f : raw;
    float yc = ysoft[i * C_CLS + c] + scale * v;
    float oh = (ytrue[i] == c) ? 1.f : 0.f;
    float ys = load_mask(maskp, flag[0], i) ? oh : yc;
    outh[i * 64 + c] = __float2half_rn(ys);
  }
}

// ---- launch ---------------------------------------------------------------
extern "C" void kernel_launch(void* const* d_in, const int* in_sizes, int n_in,
                              void* d_out, int out_size, void* d_ws, size_t ws_size,
                              hipStream_t stream) {
  const int* y_true = (const int*)d_in[0];
  const float* y_soft = (const float*)d_in[1];
  const void* maskp = d_in[2];
  const int* ei = (const int*)d_in[3];
  const float* ew = (const float*)d_in[4];
  const int n = in_sizes[0];
  const int E = in_sizes[4];
  const int* row = ei;
  const int* col = ei + E;
  const int half = n / 2;
  const int n2 = 2 * n;

  char* ws = (char*)d_ws;
  size_t o = 0;
  auto alloc = [&](size_t bytes) -> void* {
    void* p = ws + o;
    o += (bytes + 255) & ~(size_t)255;
    return p;
  };
  H4* xA16 = (H4*)alloc((size_t)n * 128);       // fp16-padded ping buffer
  H4* tmp = (H4*)alloc((size_t)n * 80);         // pass-0 partial acc (fp16)
  unsigned* eg = (unsigned*)alloc((size_t)E * 4);
  float* dis = (float*)alloc((size_t)n * 4);
  int* cnt2 = (int*)alloc((size_t)n2 * 4);
  float* sig = (float*)alloc(4);
  int* numel = (int*)alloc(4);
  int* flag = (int*)alloc(4);
  int* rp2 = (int*)alloc((size_t)(n2 + 1) * 4);
  int* cur2 = (int*)alloc((size_t)n2 * 4);
  int* part = (int*)alloc(4096);
  H4* out16 = (H4*)d_out;  // d_out region doubles as fp16 pong (12.8MB < 16MB)

  hipMemsetAsync(cnt2, 0, (size_t)n2 * 4, stream);
  hipMemsetAsync(sig, 0, 4, stream);
  hipMemsetAsync(numel, 0, 4, stream);

  const int be = (E + 255) / 256;
  const int bn = (n + 255) / 256;
  const int bn2 = (n2 + 255) / 256;
  const int bp = (n + 31) / 32;         // prop blocks (320 thr, 32 rows)
  const int bsc = (n + RPB - 1) / RPB;  // scale_kernel blocks

  detect_kernel<<<1, 256, 0, stream>>>((const unsigned int*)maskp, flag);
  hist_kernel<<<be, 256, 0, stream>>>(row, col, cnt2, E, half);
  scan1_kernel<<<bn2, 256, 0, stream>>>(cnt2, rp2, part, n2);
  scan2_kernel<<<1, 1024, 0, stream>>>(part, bn2);
  scan3_kernel<<<bn2, 256, 0, stream>>>(rp2, cur2, part, n2, E);
  scatter_kernel<<<be, 256, 0, stream>>>(row, col, ew, cur2, eg, E, half);
  deg_rsqrt_kernel<<<bn, 256, 0, stream>>>(eg, rp2, dis, n);
  norm_kernel<<<bn, 256, 0, stream>>>(eg, rp2, dis, n);
  init_error_kernel<<<512, 256, 0, stream>>>(xA16, (const float4*)y_soft,
                                             y_true, maskp, flag, sig, numel, n);

  // Phase 1 (fp16, two passes/step): correct, alpha=0.9, clip. Ends in xA16.
  H4* ha = xA16;
  H4* hb = out16;
  for (int k = 0; k < 10; ++k) {
    prop_pass0<<<bp, 320, 0, stream>>>(ha, tmp, rp2, eg, n);
    prop_pass1<0, 1><<<bp, 320, 0, stream>>>(ha, (void*)hb, tmp, rp2, eg, 0.9f, n);
    H4* t = ha; ha = hb; hb = t;
  }
  // ha == xA16 (smoothed, fp16). Scale + y_s written fp16-padded into d_out.
  scale_kernel<<<bsc, 256, 0, stream>>>((const __half*)ha, (__half*)d_out, y_soft,
                                        y_true, maskp, flag, sig, numel, n);

  // Phase 2 (fp16, two passes/step): smooth, alpha=0.8, softmax.
  ha = out16;
  hb = xA16;
  for (int k = 0; k < 9; ++k) {
    prop_pass0<<<bp, 320, 0, stream>>>(ha, tmp, rp2, eg, n);
    prop_pass1<1, 1><<<bp, 320, 0, stream>>>(ha, (void*)hb, tmp, rp2, eg, 0.8f, n);
    H4* t = ha; ha = hb; hb = t;
  }
  // after 9 steps: ha == xA16. Final step writes fp32 into d_out.
  prop_pass0<<<bp, 320, 0, stream>>>(ha, tmp, rp2, eg, n);
  prop_pass1<1, 0><<<bp, 320, 0, stream>>>(ha, d_out, tmp, rp2, eg, 0.8f, n);
}

// Round 13
// 992.965 us; speedup vs baseline: 1.1548x; 1.1548x over previous
//
#include <hip/hip_runtime.h>
#include <hip/hip_fp16.h>
#include <math.h>

#define C_CLS 40
#define RPB 6   // rows per 256-thread block in scale_kernel

struct __align__(8) H4 { __half2 a; __half2 b; };  // 4 halves

// packed edge: low 17 bits = col (N < 2^17), high 15 bits = fp16 weight
// without sign bit (weights always >= 0).
static __device__ __forceinline__ float h15f(unsigned b) {
  union { unsigned short s; __half h; } u;
  u.s = (unsigned short)b;
  return __half2float(u.h);
}
static __device__ __forceinline__ unsigned f2h15(float w) {
  union { __half h; unsigned short s; } u;
  u.h = __float2half_rn(w);
  return (unsigned)u.s;  // sign bit is 0 for w >= 0
}

// ---- runtime mask element-size handling ------------------------------------
static __device__ __forceinline__ bool load_mask(const void* p, int esz, int i) {
  if (esz == 1) return ((const unsigned char*)p)[i] != 0;
  return ((const unsigned int*)p)[i] != 0u;  // works for int32 0/1 and f32 0.0/1.0
}

__global__ void detect_kernel(const unsigned int* m, int* flag) {
  __shared__ int bad;
  if (threadIdx.x == 0) bad = 0;
  __syncthreads();
  unsigned int v = m[threadIdx.x];
  if (!(v == 0u || v == 1u || v == 0x3F800000u)) bad = 1;  // benign race
  __syncthreads();
  if (threadIdx.x == 0) flag[0] = bad ? 1 : 4;  // element size in bytes
}

// ---- CSR build (simple; hist is atomic-rate bound, scatter sector-bound) ---
__global__ void hist_kernel(const int* __restrict__ row, int* __restrict__ cnt, int E) {
  int e = blockIdx.x * blockDim.x + threadIdx.x;
  if (e < E) atomicAdd(&cnt[row[e]], 1);
}

__global__ void scan1_kernel(const int* __restrict__ cnt, int* __restrict__ rp,
                             int* __restrict__ part, int n) {
  __shared__ int sh[256];
  int gid = blockIdx.x * 256 + threadIdx.x;
  int v = (gid < n) ? cnt[gid] : 0;
  sh[threadIdx.x] = v;
  __syncthreads();
  for (int o = 1; o < 256; o <<= 1) {
    int t = (threadIdx.x >= o) ? sh[threadIdx.x - o] : 0;
    __syncthreads();
    sh[threadIdx.x] += t;
    __syncthreads();
  }
  if (gid < n) rp[gid] = sh[threadIdx.x] - v;  // exclusive within block
  if (threadIdx.x == 255) part[blockIdx.x] = sh[255];
}

__global__ void scan2_kernel(int* part, int B) {
  __shared__ int sh[1024];
  int t = threadIdx.x;
  int v = (t < B) ? part[t] : 0;
  sh[t] = v;
  __syncthreads();
  for (int o = 1; o < 1024; o <<= 1) {
    int u = (t >= o) ? sh[t - o] : 0;
    __syncthreads();
    sh[t] += u;
    __syncthreads();
  }
  if (t < B) part[t] = sh[t] - v;  // exclusive block offsets
}

__global__ void scan3_kernel(int* __restrict__ rp, int* __restrict__ cur,
                             const int* __restrict__ part, int n, int E) {
  int gid = blockIdx.x * 256 + threadIdx.x;
  if (gid < n) {
    int v = rp[gid] + part[blockIdx.x];
    rp[gid] = v;
    cur[gid] = v;
  }
  if (gid == 0) rp[n] = E;
}

__global__ void scatter_kernel(const int* __restrict__ row, const int* __restrict__ col,
                               const float* __restrict__ w,
                               int* __restrict__ cursor, unsigned* __restrict__ eg, int E) {
  int e = blockIdx.x * blockDim.x + threadIdx.x;
  if (e < E) {
    int r = row[e];
    int pos = atomicAdd(&cursor[r], 1);
    eg[pos] = (unsigned)col[e] | (f2h15(w[e]) << 17);
  }
}

// deg[i] = sum of (fp16) w over row i's CSR segment; dis[i] = rsqrt(deg).
__global__ void deg_rsqrt_kernel(const unsigned* __restrict__ eg, const int* __restrict__ rp,
                                 float* __restrict__ dis, int n) {
  int i = blockIdx.x * blockDim.x + threadIdx.x;
  if (i < n) {
    float s = 0.f;
    int e1 = rp[i + 1];
    for (int e = rp[i]; e < e1; ++e) s += h15f(eg[e] >> 17);
    dis[i] = (s > 0.f) ? rsqrtf(s) : 0.f;
  }
}

// w' = dis[r] * w * dis[c], re-encoded in place.
__global__ void norm_kernel(unsigned* __restrict__ eg, const int* __restrict__ rp,
                            const float* __restrict__ dis, int n) {
  int i = blockIdx.x * blockDim.x + threadIdx.x;
  if (i < n) {
    float dr = dis[i];
    int e1 = rp[i + 1];
    for (int e = rp[i]; e < e1; ++e) {
      unsigned u = eg[e];
      unsigned c = u & 0x1FFFFu;
      float w = dr * h15f(u >> 17) * dis[c];
      eg[e] = c | (f2h15(w) << 17);
    }
  }
}

// ---- error init (fp16-padded rows) + sigma numerator + mask count ----------
__global__ void __launch_bounds__(256) init_error_kernel(
    H4* __restrict__ x16, const float4* __restrict__ ysoft4,
    const int* __restrict__ ytrue, const void* maskp,
    const int* __restrict__ flag, float* __restrict__ sig,
    int* __restrict__ numel, int n) {
  const int esz = flag[0];
  const int total = n * 10;  // H4 chunks
  float asum = 0.f;
  int cnt = 0;
  for (int q = blockIdx.x * blockDim.x + threadIdx.x; q < total;
       q += gridDim.x * blockDim.x) {
    int i = q / 10;
    int c4 = q - i * 10;
    float4 e = make_float4(0.f, 0.f, 0.f, 0.f);
    if (load_mask(maskp, esz, i)) {
      float4 p = ysoft4[q];
      int t = ytrue[i];
      int cb = c4 * 4;
      e.x = ((t == cb) ? 1.f : 0.f) - p.x;
      e.y = ((t == cb + 1) ? 1.f : 0.f) - p.y;
      e.z = ((t == cb + 2) ? 1.f : 0.f) - p.z;
      e.w = ((t == cb + 3) ? 1.f : 0.f) - p.w;
      if (c4 == 0) cnt++;
    }
    H4 h;
    h.a = __floats2half2_rn(e.x, e.y);
    h.b = __floats2half2_rn(e.z, e.w);
    x16[i * 16 + c4] = h;
    asum += fabsf(e.x) + fabsf(e.y) + fabsf(e.z) + fabsf(e.w);
  }
  for (int o = 32; o > 0; o >>= 1) {
    asum += __shfl_down(asum, o);
    cnt += __shfl_down(cnt, o);
  }
  __shared__ float swf[4];
  __shared__ int swi[4];
  int lane = threadIdx.x & 63, wv = threadIdx.x >> 6;
  if (lane == 0) { swf[wv] = asum; swi[wv] = cnt; }
  __syncthreads();
  if (threadIdx.x == 0) {
    atomicAdd(sig, swf[0] + swf[1] + swf[2] + swf[3]);
    atomicAdd(numel, swi[0] + swi[1] + swi[2] + swi[3]);
  }
}

// ---- phase-1 propagation step (fp16 storage): clip[-1,1] -------------------
// 10 lanes/row, H4 per lane, 128B-padded rows => one line per row-gather.
__global__ void __launch_bounds__(320) prop_h_clip(const H4* __restrict__ xin,
                                                   H4* __restrict__ xout,
                                                   const int* __restrict__ rp,
                                                   const unsigned* __restrict__ eg,
                                                   float alpha, int n) {
  const int t = threadIdx.x;
  const int lr = t / 10;       // 0..31
  const int c4 = t - lr * 10;  // 0..9
  const int i = blockIdx.x * 32 + lr;
  if (i >= n) return;
  int e0 = rp[i], e1 = rp[i + 1];
  H4 hs = xin[i * 16 + c4];
  float2 s0 = __half22float2(hs.a), s1 = __half22float2(hs.b);
  float4 acc = make_float4(0.f, 0.f, 0.f, 0.f);
  int e = e0;
  for (; e + 3 < e1; e += 4) {  // 4 outstanding gathers
    unsigned u0 = eg[e], u1 = eg[e + 1], u2 = eg[e + 2], u3 = eg[e + 3];
    H4 h0 = xin[(u0 & 0x1FFFFu) * 16 + c4];
    H4 h1 = xin[(u1 & 0x1FFFFu) * 16 + c4];
    H4 h2 = xin[(u2 & 0x1FFFFu) * 16 + c4];
    H4 h3 = xin[(u3 & 0x1FFFFu) * 16 + c4];
    float w0 = h15f(u0 >> 17), w1 = h15f(u1 >> 17),
          w2 = h15f(u2 >> 17), w3 = h15f(u3 >> 17);
    float2 a0 = __half22float2(h0.a), b0 = __half22float2(h0.b);
    float2 a1 = __half22float2(h1.a), b1 = __half22float2(h1.b);
    float2 a2 = __half22float2(h2.a), b2 = __half22float2(h2.b);
    float2 a3 = __half22float2(h3.a), b3 = __half22float2(h3.b);
    acc.x = fmaf(w0, a0.x, acc.x); acc.y = fmaf(w0, a0.y, acc.y);
    acc.z = fmaf(w0, b0.x, acc.z); acc.w = fmaf(w0, b0.y, acc.w);
    acc.x = fmaf(w1, a1.x, acc.x); acc.y = fmaf(w1, a1.y, acc.y);
    acc.z = fmaf(w1, b1.x, acc.z); acc.w = fmaf(w1, b1.y, acc.w);
    acc.x = fmaf(w2, a2.x, acc.x); acc.y = fmaf(w2, a2.y, acc.y);
    acc.z = fmaf(w2, b2.x, acc.z); acc.w = fmaf(w2, b2.y, acc.w);
    acc.x = fmaf(w3, a3.x, acc.x); acc.y = fmaf(w3, a3.y, acc.y);
    acc.z = fmaf(w3, b3.x, acc.z); acc.w = fmaf(w3, b3.y, acc.w);
  }
  for (; e < e1; ++e) {
    unsigned u = eg[e];
    H4 h = xin[(u & 0x1FFFFu) * 16 + c4];
    float w = h15f(u >> 17);
    float2 a = __half22float2(h.a), b = __half22float2(h.b);
    acc.x = fmaf(w, a.x, acc.x); acc.y = fmaf(w, a.y, acc.y);
    acc.z = fmaf(w, b.x, acc.z); acc.w = fmaf(w, b.y, acc.w);
  }
  float beta = 1.f - alpha;
  float vx = fminf(1.f, fmaxf(-1.f, alpha * acc.x + beta * s0.x));
  float vy = fminf(1.f, fmaxf(-1.f, alpha * acc.y + beta * s0.y));
  float vz = fminf(1.f, fmaxf(-1.f, alpha * acc.z + beta * s1.x));
  float vw = fminf(1.f, fmaxf(-1.f, alpha * acc.w + beta * s1.y));
  H4 o;
  o.a = __floats2half2_rn(vx, vy);
  o.b = __floats2half2_rn(vz, vw);
  xout[i * 16 + c4] = o;
}

// ---- phase-2 propagation step (fp16 storage): row softmax ------------------
// OUT16: write fp16 (steps 1..9) or fp32 into d_out layout (final step).
template <int OUT16>
__global__ void __launch_bounds__(320) prop_h_soft(const H4* __restrict__ xin,
                                                   void* __restrict__ xout,
                                                   const int* __restrict__ rp,
                                                   const unsigned* __restrict__ eg,
                                                   float alpha, int n) {
  const int t = threadIdx.x;
  const int lr = t / 10;       // 0..31
  const int c4 = t - lr * 10;  // 0..9
  const int i = blockIdx.x * 32 + lr;
  const bool active = (i < n);
  float4 v = make_float4(0.f, 0.f, 0.f, 0.f);
  if (active) {
    int e0 = rp[i], e1 = rp[i + 1];
    H4 hs = xin[i * 16 + c4];
    float2 s0 = __half22float2(hs.a), s1 = __half22float2(hs.b);
    float4 acc = make_float4(0.f, 0.f, 0.f, 0.f);
    int e = e0;
    for (; e + 3 < e1; e += 4) {
      unsigned u0 = eg[e], u1 = eg[e + 1], u2 = eg[e + 2], u3 = eg[e + 3];
      H4 h0 = xin[(u0 & 0x1FFFFu) * 16 + c4];
      H4 h1 = xin[(u1 & 0x1FFFFu) * 16 + c4];
      H4 h2 = xin[(u2 & 0x1FFFFu) * 16 + c4];
      H4 h3 = xin[(u3 & 0x1FFFFu) * 16 + c4];
      float w0 = h15f(u0 >> 17), w1 = h15f(u1 >> 17),
            w2 = h15f(u2 >> 17), w3 = h15f(u3 >> 17);
      float2 a0 = __half22float2(h0.a), b0 = __half22float2(h0.b);
      float2 a1 = __half22float2(h1.a), b1 = __half22float2(h1.b);
      float2 a2 = __half22float2(h2.a), b2 = __half22float2(h2.b);
      float2 a3 = __half22float2(h3.a), b3 = __half22float2(h3.b);
      acc.x = fmaf(w0, a0.x, acc.x); acc.y = fmaf(w0, a0.y, acc.y);
      acc.z = fmaf(w0, b0.x, acc.z); acc.w = fmaf(w0, b0.y, acc.w);
      acc.x = fmaf(w1, a1.x, acc.x); acc.y = fmaf(w1, a1.y, acc.y);
      acc.z = fmaf(w1, b1.x, acc.z); acc.w = fmaf(w1, b1.y, acc.w);
      acc.x = fmaf(w2, a2.x, acc.x); acc.y = fmaf(w2, a2.y, acc.y);
      acc.z = fmaf(w2, b2.x, acc.z); acc.w = fmaf(w2, b2.y, acc.w);
      acc.x = fmaf(w3, a3.x, acc.x); acc.y = fmaf(w3, a3.y, acc.y);
      acc.z = fmaf(w3, b3.x, acc.z); acc.w = fmaf(w3, b3.y, acc.w);
    }
    for (; e < e1; ++e) {
      unsigned u = eg[e];
      H4 h = xin[(u & 0x1FFFFu) * 16 + c4];
      float w = h15f(u >> 17);
      float2 a = __half22float2(h.a), b = __half22float2(h.b);
      acc.x = fmaf(w, a.x, acc.x); acc.y = fmaf(w, a.y, acc.y);
      acc.z = fmaf(w, b.x, acc.z); acc.w = fmaf(w, b.y, acc.w);
    }
    float beta = 1.f - alpha;
    v.x = alpha * acc.x + beta * s0.x;
    v.y = alpha * acc.y + beta * s0.y;
    v.z = alpha * acc.z + beta * s1.x;
    v.w = alpha * acc.w + beta * s1.y;
  }
  // row softmax via LDS
  __shared__ float sh[32][10];
  __shared__ float shr[32];
  float lmax = fmaxf(fmaxf(v.x, v.y), fmaxf(v.z, v.w));
  if (active) sh[lr][c4] = lmax;
  __syncthreads();
  if (active && c4 == 0) {
    float m = sh[lr][0];
#pragma unroll
    for (int k = 1; k < 10; ++k) m = fmaxf(m, sh[lr][k]);
    shr[lr] = m;
  }
  __syncthreads();
  float m = active ? shr[lr] : 0.f;
  float ex = __expf(v.x - m), ey = __expf(v.y - m),
        ez = __expf(v.z - m), ew = __expf(v.w - m);
  if (active) sh[lr][c4] = ex + ey + ez + ew;
  __syncthreads();
  if (active && c4 == 0) {
    float s = sh[lr][0];
#pragma unroll
    for (int k = 1; k < 10; ++k) s += sh[lr][k];
    shr[lr] = s;
  }
  __syncthreads();
  if (active) {
    float inv = 1.f / shr[lr];
    if (OUT16) {
      H4 o;
      o.a = __floats2half2_rn(ex * inv, ey * inv);
      o.b = __floats2half2_rn(ez * inv, ew * inv);
      ((H4*)xout)[i * 16 + c4] = o;
    } else {
      ((float4*)xout)[i * 10 + c4] =
          make_float4(ex * inv, ey * inv, ez * inv, ew * inv);
    }
  }
}

// ---- scale + y_s (fp16 smoothed in, fp16-padded y_s out) -------------------
__global__ void __launch_bounds__(256) scale_kernel(const __half* __restrict__ smh,
                                                    __half* __restrict__ outh,
                                                    const float* __restrict__ ysoft,
                                                    const int* __restrict__ ytrue,
                                                    const void* maskp,
                                                    const int* __restrict__ flag,
                                                    const float* __restrict__ sig,
                                                    const int* __restrict__ numel, int n) {
  int t = threadIdx.x;
  int lr = t / C_CLS, c = t - lr * C_CLS;
  int i = blockIdx.x * RPB + lr;
  bool active = (lr < RPB) && (i < n);
  __shared__ float sh[RPB][C_CLS];
  __shared__ float shd[RPB];
  float v = 0.f;
  if (active) {
    v = __half2float(smh[i * 64 + c]);
    sh[lr][c] = fabsf(v);
  }
  __syncthreads();
  if (active && c == 0) {
    float d = 0.f;
#pragma unroll
    for (int k = 0; k < C_CLS; ++k) d += sh[lr][k];
    shd[lr] = d;
  }
  __syncthreads();
  if (active) {
    float denom = shd[lr];
    float sigma = sig[0] / (float)numel[0];
    float raw = sigma / ((denom > 0.f) ? denom : 1.f);
    float scale = (denom <= 0.f || raw > 1000.f) ? 1.f : raw;
    float yc = ysoft[i * C_CLS + c] + scale * v;
    float oh = (ytrue[i] == c) ? 1.f : 0.f;
    float ys = load_mask(maskp, flag[0], i) ? oh : yc;
    outh[i * 64 + c] = __float2half_rn(ys);
  }
}

// ---- launch ---------------------------------------------------------------
extern "C" void kernel_launch(void* const* d_in, const int* in_sizes, int n_in,
                              void* d_out, int out_size, void* d_ws, size_t ws_size,
                              hipStream_t stream) {
  const int* y_true = (const int*)d_in[0];
  const float* y_soft = (const float*)d_in[1];
  const void* maskp = d_in[2];
  const int* ei = (const int*)d_in[3];
  const float* ew = (const float*)d_in[4];
  const int n = in_sizes[0];
  const int E = in_sizes[4];
  const int* row = ei;
  const int* col = ei + E;

  char* ws = (char*)d_ws;
  size_t o = 0;
  auto alloc = [&](size_t bytes) -> void* {
    void* p = ws + o;
    o += (bytes + 255) & ~(size_t)255;
    return p;
  };
  H4* xA16 = (H4*)alloc((size_t)n * 128);  // fp16-padded ping buffer
  unsigned* eg = (unsigned*)alloc((size_t)E * 4);
  float* dis = (float*)alloc((size_t)n * 4);
  int* cnt = (int*)alloc((size_t)n * 4);
  float* sig = (float*)alloc(4);
  int* numel = (int*)alloc(4);
  int* flag = (int*)alloc(4);
  int* rp = (int*)alloc((size_t)(n + 1) * 4);
  int* cur = (int*)alloc((size_t)n * 4);
  int* part = (int*)alloc(4096);
  H4* out16 = (H4*)d_out;  // d_out region doubles as fp16 pong (12.8MB < 16MB)

  hipMemsetAsync(cnt, 0, (size_t)n * 4, stream);
  hipMemsetAsync(sig, 0, 4, stream);
  hipMemsetAsync(numel, 0, 4, stream);

  const int be = (E + 255) / 256;
  const int bn = (n + 255) / 256;
  const int bp = (n + 31) / 32;         // prop blocks (320 thr, 32 rows)
  const int bsc = (n + RPB - 1) / RPB;  // scale_kernel blocks

  detect_kernel<<<1, 256, 0, stream>>>((const unsigned int*)maskp, flag);
  hist_kernel<<<be, 256, 0, stream>>>(row, cnt, E);
  scan1_kernel<<<bn, 256, 0, stream>>>(cnt, rp, part, n);
  scan2_kernel<<<1, 1024, 0, stream>>>(part, bn);
  scan3_kernel<<<bn, 256, 0, stream>>>(rp, cur, part, n, E);
  scatter_kernel<<<be, 256, 0, stream>>>(row, col, ew, cur, eg, E);
  deg_rsqrt_kernel<<<bn, 256, 0, stream>>>(eg, rp, dis, n);
  norm_kernel<<<bn, 256, 0, stream>>>(eg, rp, dis, n);
  init_error_kernel<<<512, 256, 0, stream>>>(xA16, (const float4*)y_soft,
                                             y_true, maskp, flag, sig, numel, n);

  // Phase 1 (fp16): correct, alpha=0.9, clip. xA16 <-> out16; ends in xA16.
  H4* ha = xA16;
  H4* hb = out16;
  for (int k = 0; k < 10; ++k) {
    prop_h_clip<<<bp, 320, 0, stream>>>(ha, hb, rp, eg, 0.9f, n);
    H4* t = ha; ha = hb; hb = t;
  }
  // ha == xA16 (smoothed, fp16). Scale + y_s written fp16-padded into d_out.
  scale_kernel<<<bsc, 256, 0, stream>>>((const __half*)ha, (__half*)d_out, y_soft,
                                        y_true, maskp, flag, sig, numel, n);

  // Phase 2 (fp16): smooth, alpha=0.8, softmax.
  // steps 1..9 fp16 ping-pong starting at d_out region; step 10 -> fp32 d_out.
  ha = out16;
  hb = xA16;
  for (int k = 0; k < 9; ++k) {
    prop_h_soft<1><<<bp, 320, 0, stream>>>(ha, (void*)hb, rp, eg, 0.8f, n);
    H4* t = ha; ha = hb; hb = t;
  }
  // after 9 steps: ha == xA16. Final step writes fp32 into d_out.
  prop_h_soft<0><<<bp, 320, 0, stream>>>(ha, d_out, rp, eg, 0.8f, n);
}

// Round 14
// 946.865 us; speedup vs baseline: 1.2111x; 1.0487x over previous
//
#include <hip/hip_runtime.h>
#include <hip/hip_fp16.h>
#include <math.h>

#define C_CLS 40
#define RPB 6      // rows per 256-thread block in scale_kernel
#define NCHUNK 2048  // edge chunks per group in the 8-group build sweeps

struct __align__(8) H4 { __half2 a; __half2 b; };  // 4 halves

// packed edge: low 17 bits = col (N < 2^17), high 15 bits = fp16 weight
// without sign bit (weights always >= 0).
static __device__ __forceinline__ float h15f(unsigned b) {
  union { unsigned short s; __half h; } u;
  u.s = (unsigned short)b;
  return __half2float(u.h);
}
static __device__ __forceinline__ unsigned f2h15(float w) {
  union { __half h; unsigned short s; } u;
  u.h = __float2half_rn(w);
  return (unsigned)u.s;  // sign bit is 0 for w >= 0
}

// ---- runtime mask element-size handling ------------------------------------
static __device__ __forceinline__ bool load_mask(const void* p, int esz, int i) {
  if (esz == 1) return ((const unsigned char*)p)[i] != 0;
  return ((const unsigned int*)p)[i] != 0u;  // works for int32 0/1 and f32 0.0/1.0
}

__global__ void detect_kernel(const unsigned int* m, int* flag) {
  __shared__ int bad;
  if (threadIdx.x == 0) bad = 0;
  __syncthreads();
  unsigned int v = m[threadIdx.x];
  if (!(v == 0u || v == 1u || v == 0x3F800000u)) bad = 1;  // benign race
  __syncthreads();
  if (threadIdx.x == 0) flag[0] = bad ? 1 : 4;  // element size in bytes
}

// ---- CSR build: XCD-range-partitioned hist + scatter -----------------------
// group g = blockIdx & 7 (dispatch round-robins blocks over the 8 XCDs, so
// group g's blocks co-reside on XCD g — perf heuristic, not correctness).
// Group g handles rows [g*n/8, (g+1)*n/8): its cnt/cursor counters and its
// eg output region are touched by ONE XCD only => L2-resident atomics, full
// sector fill before eviction (kills the 65 B/edge cross-XCD write blowup).
// Cost: each group sweeps all E edges (8x streaming re-read, L3-served).
__global__ void __launch_bounds__(256) hist_kernel(const int* __restrict__ row,
                                                   int* __restrict__ cnt,
                                                   int E, int n, int CE) {
  const int g = blockIdx.x & 7;
  const int chunk = blockIdx.x >> 3;
  const int lo = (int)(((long long)g * n) >> 3);
  const int hi = (g == 7) ? n : (int)(((long long)(g + 1) * n) >> 3);
  const int e0 = chunk * CE;
  const int e1 = min(E, e0 + CE);
  for (int e = e0 + (int)threadIdx.x; e < e1; e += 256) {
    int r = row[e];
    if (r >= lo && r < hi) atomicAdd(&cnt[r], 1);
  }
}

__global__ void scan1_kernel(const int* __restrict__ cnt, int* __restrict__ rp,
                             int* __restrict__ part, int n) {
  __shared__ int sh[256];
  int gid = blockIdx.x * 256 + threadIdx.x;
  int v = (gid < n) ? cnt[gid] : 0;
  sh[threadIdx.x] = v;
  __syncthreads();
  for (int o = 1; o < 256; o <<= 1) {
    int t = (threadIdx.x >= o) ? sh[threadIdx.x - o] : 0;
    __syncthreads();
    sh[threadIdx.x] += t;
    __syncthreads();
  }
  if (gid < n) rp[gid] = sh[threadIdx.x] - v;  // exclusive within block
  if (threadIdx.x == 255) part[blockIdx.x] = sh[255];
}

__global__ void scan2_kernel(int* part, int B) {
  __shared__ int sh[1024];
  int t = threadIdx.x;
  int v = (t < B) ? part[t] : 0;
  sh[t] = v;
  __syncthreads();
  for (int o = 1; o < 1024; o <<= 1) {
    int u = (t >= o) ? sh[t - o] : 0;
    __syncthreads();
    sh[t] += u;
    __syncthreads();
  }
  if (t < B) part[t] = sh[t] - v;  // exclusive block offsets
}

__global__ void scan3_kernel(int* __restrict__ rp, int* __restrict__ cur,
                             const int* __restrict__ part, int n, int E) {
  int gid = blockIdx.x * 256 + threadIdx.x;
  if (gid < n) {
    int v = rp[gid] + part[blockIdx.x];
    rp[gid] = v;
    cur[gid] = v;
  }
  if (gid == 0) rp[n] = E;
}

__global__ void __launch_bounds__(256) scatter_kernel(const int* __restrict__ row,
                                                      const int* __restrict__ col,
                                                      const float* __restrict__ w,
                                                      int* __restrict__ cursor,
                                                      unsigned* __restrict__ eg,
                                                      int E, int n, int CE) {
  const int g = blockIdx.x & 7;
  const int chunk = blockIdx.x >> 3;
  const int lo = (int)(((long long)g * n) >> 3);
  const int hi = (g == 7) ? n : (int)(((long long)(g + 1) * n) >> 3);
  const int e0 = chunk * CE;
  const int e1 = min(E, e0 + CE);
  for (int e = e0 + (int)threadIdx.x; e < e1; e += 256) {
    int r = row[e];
    if (r >= lo && r < hi) {
      int pos = atomicAdd(&cursor[r], 1);
      eg[pos] = (unsigned)col[e] | (f2h15(w[e]) << 17);
    }
  }
}

// deg[i] = sum of (fp16) w over row i's CSR segment; dis[i] = rsqrt(deg).
__global__ void deg_rsqrt_kernel(const unsigned* __restrict__ eg, const int* __restrict__ rp,
                                 float* __restrict__ dis, int n) {
  int i = blockIdx.x * blockDim.x + threadIdx.x;
  if (i < n) {
    float s = 0.f;
    int e1 = rp[i + 1];
    for (int e = rp[i]; e < e1; ++e) s += h15f(eg[e] >> 17);
    dis[i] = (s > 0.f) ? rsqrtf(s) : 0.f;
  }
}

// w' = dis[r] * w * dis[c], re-encoded in place.
__global__ void norm_kernel(unsigned* __restrict__ eg, const int* __restrict__ rp,
                            const float* __restrict__ dis, int n) {
  int i = blockIdx.x * blockDim.x + threadIdx.x;
  if (i < n) {
    float dr = dis[i];
    int e1 = rp[i + 1];
    for (int e = rp[i]; e < e1; ++e) {
      unsigned u = eg[e];
      unsigned c = u & 0x1FFFFu;
      float w = dr * h15f(u >> 17) * dis[c];
      eg[e] = c | (f2h15(w) << 17);
    }
  }
}

// ---- error init (fp16-padded rows) + sigma numerator + mask count ----------
__global__ void __launch_bounds__(256) init_error_kernel(
    H4* __restrict__ x16, const float4* __restrict__ ysoft4,
    const int* __restrict__ ytrue, const void* maskp,
    const int* __restrict__ flag, float* __restrict__ sig,
    int* __restrict__ numel, int n) {
  const int esz = flag[0];
  const int total = n * 10;  // H4 chunks
  float asum = 0.f;
  int cnt = 0;
  for (int q = blockIdx.x * blockDim.x + threadIdx.x; q < total;
       q += gridDim.x * blockDim.x) {
    int i = q / 10;
    int c4 = q - i * 10;
    float4 e = make_float4(0.f, 0.f, 0.f, 0.f);
    if (load_mask(maskp, esz, i)) {
      float4 p = ysoft4[q];
      int t = ytrue[i];
      int cb = c4 * 4;
      e.x = ((t == cb) ? 1.f : 0.f) - p.x;
      e.y = ((t == cb + 1) ? 1.f : 0.f) - p.y;
      e.z = ((t == cb + 2) ? 1.f : 0.f) - p.z;
      e.w = ((t == cb + 3) ? 1.f : 0.f) - p.w;
      if (c4 == 0) cnt++;
    }
    H4 h;
    h.a = __floats2half2_rn(e.x, e.y);
    h.b = __floats2half2_rn(e.z, e.w);
    x16[i * 16 + c4] = h;
    asum += fabsf(e.x) + fabsf(e.y) + fabsf(e.z) + fabsf(e.w);
  }
  for (int o = 32; o > 0; o >>= 1) {
    asum += __shfl_down(asum, o);
    cnt += __shfl_down(cnt, o);
  }
  __shared__ float swf[4];
  __shared__ int swi[4];
  int lane = threadIdx.x & 63, wv = threadIdx.x >> 6;
  if (lane == 0) { swf[wv] = asum; swi[wv] = cnt; }
  __syncthreads();
  if (threadIdx.x == 0) {
    atomicAdd(sig, swf[0] + swf[1] + swf[2] + swf[3]);
    atomicAdd(numel, swi[0] + swi[1] + swi[2] + swi[3]);
  }
}

// ---- phase-1 propagation step (fp16 storage): clip[-1,1] -------------------
// 10 lanes/row, H4 per lane, 128B-padded rows => one line per row-gather.
__global__ void __launch_bounds__(320) prop_h_clip(const H4* __restrict__ xin,
                                                   H4* __restrict__ xout,
                                                   const int* __restrict__ rp,
                                                   const unsigned* __restrict__ eg,
                                                   float alpha, int n) {
  const int t = threadIdx.x;
  const int lr = t / 10;       // 0..31
  const int c4 = t - lr * 10;  // 0..9
  const int i = blockIdx.x * 32 + lr;
  if (i >= n) return;
  int e0 = rp[i], e1 = rp[i + 1];
  H4 hs = xin[i * 16 + c4];
  float2 s0 = __half22float2(hs.a), s1 = __half22float2(hs.b);
  float4 acc = make_float4(0.f, 0.f, 0.f, 0.f);
  int e = e0;
  for (; e + 3 < e1; e += 4) {  // 4 outstanding gathers
    unsigned u0 = eg[e], u1 = eg[e + 1], u2 = eg[e + 2], u3 = eg[e + 3];
    H4 h0 = xin[(u0 & 0x1FFFFu) * 16 + c4];
    H4 h1 = xin[(u1 & 0x1FFFFu) * 16 + c4];
    H4 h2 = xin[(u2 & 0x1FFFFu) * 16 + c4];
    H4 h3 = xin[(u3 & 0x1FFFFu) * 16 + c4];
    float w0 = h15f(u0 >> 17), w1 = h15f(u1 >> 17),
          w2 = h15f(u2 >> 17), w3 = h15f(u3 >> 17);
    float2 a0 = __half22float2(h0.a), b0 = __half22float2(h0.b);
    float2 a1 = __half22float2(h1.a), b1 = __half22float2(h1.b);
    float2 a2 = __half22float2(h2.a), b2 = __half22float2(h2.b);
    float2 a3 = __half22float2(h3.a), b3 = __half22float2(h3.b);
    acc.x = fmaf(w0, a0.x, acc.x); acc.y = fmaf(w0, a0.y, acc.y);
    acc.z = fmaf(w0, b0.x, acc.z); acc.w = fmaf(w0, b0.y, acc.w);
    acc.x = fmaf(w1, a1.x, acc.x); acc.y = fmaf(w1, a1.y, acc.y);
    acc.z = fmaf(w1, b1.x, acc.z); acc.w = fmaf(w1, b1.y, acc.w);
    acc.x = fmaf(w2, a2.x, acc.x); acc.y = fmaf(w2, a2.y, acc.y);
    acc.z = fmaf(w2, b2.x, acc.z); acc.w = fmaf(w2, b2.y, acc.w);
    acc.x = fmaf(w3, a3.x, acc.x); acc.y = fmaf(w3, a3.y, acc.y);
    acc.z = fmaf(w3, b3.x, acc.z); acc.w = fmaf(w3, b3.y, acc.w);
  }
  for (; e < e1; ++e) {
    unsigned u = eg[e];
    H4 h = xin[(u & 0x1FFFFu) * 16 + c4];
    float w = h15f(u >> 17);
    float2 a = __half22float2(h.a), b = __half22float2(h.b);
    acc.x = fmaf(w, a.x, acc.x); acc.y = fmaf(w, a.y, acc.y);
    acc.z = fmaf(w, b.x, acc.z); acc.w = fmaf(w, b.y, acc.w);
  }
  float beta = 1.f - alpha;
  float vx = fminf(1.f, fmaxf(-1.f, alpha * acc.x + beta * s0.x));
  float vy = fminf(1.f, fmaxf(-1.f, alpha * acc.y + beta * s0.y));
  float vz = fminf(1.f, fmaxf(-1.f, alpha * acc.z + beta * s1.x));
  float vw = fminf(1.f, fmaxf(-1.f, alpha * acc.w + beta * s1.y));
  H4 o;
  o.a = __floats2half2_rn(vx, vy);
  o.b = __floats2half2_rn(vz, vw);
  xout[i * 16 + c4] = o;
}

// ---- phase-2 propagation step (fp16 storage): row softmax ------------------
// OUT16: write fp16 (steps 1..9) or fp32 into d_out layout (final step).
template <int OUT16>
__global__ void __launch_bounds__(320) prop_h_soft(const H4* __restrict__ xin,
                                                   void* __restrict__ xout,
                                                   const int* __restrict__ rp,
                                                   const unsigned* __restrict__ eg,
                                                   float alpha, int n) {
  const int t = threadIdx.x;
  const int lr = t / 10;       // 0..31
  const int c4 = t - lr * 10;  // 0..9
  const int i = blockIdx.x * 32 + lr;
  const bool active = (i < n);
  float4 v = make_float4(0.f, 0.f, 0.f, 0.f);
  if (active) {
    int e0 = rp[i], e1 = rp[i + 1];
    H4 hs = xin[i * 16 + c4];
    float2 s0 = __half22float2(hs.a), s1 = __half22float2(hs.b);
    float4 acc = make_float4(0.f, 0.f, 0.f, 0.f);
    int e = e0;
    for (; e + 3 < e1; e += 4) {
      unsigned u0 = eg[e], u1 = eg[e + 1], u2 = eg[e + 2], u3 = eg[e + 3];
      H4 h0 = xin[(u0 & 0x1FFFFu) * 16 + c4];
      H4 h1 = xin[(u1 & 0x1FFFFu) * 16 + c4];
      H4 h2 = xin[(u2 & 0x1FFFFu) * 16 + c4];
      H4 h3 = xin[(u3 & 0x1FFFFu) * 16 + c4];
      float w0 = h15f(u0 >> 17), w1 = h15f(u1 >> 17),
            w2 = h15f(u2 >> 17), w3 = h15f(u3 >> 17);
      float2 a0 = __half22float2(h0.a), b0 = __half22float2(h0.b);
      float2 a1 = __half22float2(h1.a), b1 = __half22float2(h1.b);
      float2 a2 = __half22float2(h2.a), b2 = __half22float2(h2.b);
      float2 a3 = __half22float2(h3.a), b3 = __half22float2(h3.b);
      acc.x = fmaf(w0, a0.x, acc.x); acc.y = fmaf(w0, a0.y, acc.y);
      acc.z = fmaf(w0, b0.x, acc.z); acc.w = fmaf(w0, b0.y, acc.w);
      acc.x = fmaf(w1, a1.x, acc.x); acc.y = fmaf(w1, a1.y, acc.y);
      acc.z = fmaf(w1, b1.x, acc.z); acc.w = fmaf(w1, b1.y, acc.w);
      acc.x = fmaf(w2, a2.x, acc.x); acc.y = fmaf(w2, a2.y, acc.y);
      acc.z = fmaf(w2, b2.x, acc.z); acc.w = fmaf(w2, b2.y, acc.w);
      acc.x = fmaf(w3, a3.x, acc.x); acc.y = fmaf(w3, a3.y, acc.y);
      acc.z = fmaf(w3, b3.x, acc.z); acc.w = fmaf(w3, b3.y, acc.w);
    }
    for (; e < e1; ++e) {
      unsigned u = eg[e];
      H4 h = xin[(u & 0x1FFFFu) * 16 + c4];
      float w = h15f(u >> 17);
      float2 a = __half22float2(h.a), b = __half22float2(h.b);
      acc.x = fmaf(w, a.x, acc.x); acc.y = fmaf(w, a.y, acc.y);
      acc.z = fmaf(w, b.x, acc.z); acc.w = fmaf(w, b.y, acc.w);
    }
    float beta = 1.f - alpha;
    v.x = alpha * acc.x + beta * s0.x;
    v.y = alpha * acc.y + beta * s0.y;
    v.z = alpha * acc.z + beta * s1.x;
    v.w = alpha * acc.w + beta * s1.y;
  }
  // row softmax via LDS
  __shared__ float sh[32][10];
  __shared__ float shr[32];
  float lmax = fmaxf(fmaxf(v.x, v.y), fmaxf(v.z, v.w));
  if (active) sh[lr][c4] = lmax;
  __syncthreads();
  if (active && c4 == 0) {
    float m = sh[lr][0];
#pragma unroll
    for (int k = 1; k < 10; ++k) m = fmaxf(m, sh[lr][k]);
    shr[lr] = m;
  }
  __syncthreads();
  float m = active ? shr[lr] : 0.f;
  float ex = __expf(v.x - m), ey = __expf(v.y - m),
        ez = __expf(v.z - m), ew = __expf(v.w - m);
  if (active) sh[lr][c4] = ex + ey + ez + ew;
  __syncthreads();
  if (active && c4 == 0) {
    float s = sh[lr][0];
#pragma unroll
    for (int k = 1; k < 10; ++k) s += sh[lr][k];
    shr[lr] = s;
  }
  __syncthreads();
  if (active) {
    float inv = 1.f / shr[lr];
    if (OUT16) {
      H4 o;
      o.a = __floats2half2_rn(ex * inv, ey * inv);
      o.b = __floats2half2_rn(ez * inv, ew * inv);
      ((H4*)xout)[i * 16 + c4] = o;
    } else {
      ((float4*)xout)[i * 10 + c4] =
          make_float4(ex * inv, ey * inv, ez * inv, ew * inv);
    }
  }
}

// ---- scale + y_s (fp16 smoothed in, fp16-padded y_s out) -------------------
__global__ void __launch_bounds__(256) scale_kernel(const __half* __restrict__ smh,
                                                    __half* __restrict__ outh,
                                                    const float* __restrict__ ysoft,
                                                    const int* __restrict__ ytrue,
                                                    const void* maskp,
                                                    const int* __restrict__ flag,
                                                    const float* __restrict__ sig,
                                                    const int* __restrict__ numel, int n) {
  int t = threadIdx.x;
  int lr = t / C_CLS, c = t - lr * C_CLS;
  int i = blockIdx.x * RPB + lr;
  bool active = (lr < RPB) && (i < n);
  __shared__ float sh[RPB][C_CLS];
  __shared__ float shd[RPB];
  float v = 0.f;
  if (active) {
    v = __half2float(smh[i * 64 + c]);
    sh[lr][c] = fabsf(v);
  }
  __syncthreads();
  if (active && c == 0) {
    float d = 0.f;
#pragma unroll
    for (int k = 0; k < C_CLS; ++k) d += sh[lr][k];
    shd[lr] = d;
  }
  __syncthreads();
  if (active) {
    float denom = shd[lr];
    float sigma = sig[0] / (float)numel[0];
    float raw = sigma / ((denom > 0.f) ? denom : 1.f);
    float scale = (denom <= 0.f || raw > 1000.f) ? 1.f : raw;
    float yc = ysoft[i * C_CLS + c] + scale * v;
    float oh = (ytrue[i] == c) ? 1.f : 0.f;
    float ys = load_mask(maskp, flag[0], i) ? oh : yc;
    outh[i * 64 + c] = __float2half_rn(ys);
  }
}

// ---- launch ---------------------------------------------------------------
extern "C" void kernel_launch(void* const* d_in, const int* in_sizes, int n_in,
                              void* d_out, int out_size, void* d_ws, size_t ws_size,
                              hipStream_t stream) {
  const int* y_true = (const int*)d_in[0];
  const float* y_soft = (const float*)d_in[1];
  const void* maskp = d_in[2];
  const int* ei = (const int*)d_in[3];
  const float* ew = (const float*)d_in[4];
  const int n = in_sizes[0];
  const int E = in_sizes[4];
  const int* row = ei;
  const int* col = ei + E;

  char* ws = (char*)d_ws;
  size_t o = 0;
  auto alloc = [&](size_t bytes) -> void* {
    void* p = ws + o;
    o += (bytes + 255) & ~(size_t)255;
    return p;
  };
  H4* xA16 = (H4*)alloc((size_t)n * 128);  // fp16-padded ping buffer
  unsigned* eg = (unsigned*)alloc((size_t)E * 4);
  float* dis = (float*)alloc((size_t)n * 4);
  int* cnt = (int*)alloc((size_t)n * 4);
  float* sig = (float*)alloc(4);
  int* numel = (int*)alloc(4);
  int* flag = (int*)alloc(4);
  int* rp = (int*)alloc((size_t)(n + 1) * 4);
  int* cur = (int*)alloc((size_t)n * 4);
  int* part = (int*)alloc(4096);
  H4* out16 = (H4*)d_out;  // d_out region doubles as fp16 pong (12.8MB < 16MB)

  hipMemsetAsync(cnt, 0, (size_t)n * 4, stream);
  hipMemsetAsync(sig, 0, 4, stream);
  hipMemsetAsync(numel, 0, 4, stream);

  const int bn = (n + 255) / 256;
  const int bp = (n + 31) / 32;         // prop blocks (320 thr, 32 rows)
  const int bsc = (n + RPB - 1) / RPB;  // scale_kernel blocks
  const int CE = (E + NCHUNK - 1) / NCHUNK;  // edges per chunk
  const int bgrp = NCHUNK * 8;          // 8-group build grid

  detect_kernel<<<1, 256, 0, stream>>>((const unsigned int*)maskp, flag);
  hist_kernel<<<bgrp, 256, 0, stream>>>(row, cnt, E, n, CE);
  scan1_kernel<<<bn, 256, 0, stream>>>(cnt, rp, part, n);
  scan2_kernel<<<1, 1024, 0, stream>>>(part, bn);
  scan3_kernel<<<bn, 256, 0, stream>>>(rp, cur, part, n, E);
  scatter_kernel<<<bgrp, 256, 0, stream>>>(row, col, ew, cur, eg, E, n, CE);
  deg_rsqrt_kernel<<<bn, 256, 0, stream>>>(eg, rp, dis, n);
  norm_kernel<<<bn, 256, 0, stream>>>(eg, rp, dis, n);
  init_error_kernel<<<512, 256, 0, stream>>>(xA16, (const float4*)y_soft,
                                             y_true, maskp, flag, sig, numel, n);

  // Phase 1 (fp16): correct, alpha=0.9, clip. xA16 <-> out16; ends in xA16.
  H4* ha = xA16;
  H4* hb = out16;
  for (int k = 0; k < 10; ++k) {
    prop_h_clip<<<bp, 320, 0, stream>>>(ha, hb, rp, eg, 0.9f, n);
    H4* t = ha; ha = hb; hb = t;
  }
  // ha == xA16 (smoothed, fp16). Scale + y_s written fp16-padded into d_out.
  scale_kernel<<<bsc, 256, 0, stream>>>((const __half*)ha, (__half*)d_out, y_soft,
                                        y_true, maskp, flag, sig, numel, n);

  // Phase 2 (fp16): smooth, alpha=0.8, softmax.
  // steps 1..9 fp16 ping-pong starting at d_out region; step 10 -> fp32 d_out.
  ha = out16;
  hb = xA16;
  for (int k = 0; k < 9; ++k) {
    prop_h_soft<1><<<bp, 320, 0, stream>>>(ha, (void*)hb, rp, eg, 0.8f, n);
    H4* t = ha; ha = hb; hb = t;
  }
  // after 9 steps: ha == xA16. Final step writes fp32 into d_out.
  prop_h_soft<0><<<bp, 320, 0, stream>>>(ha, d_out, rp, eg, 0.8f, n);
}